// Round 4
// baseline (1393.525 us; speedup 1.0000x reference)
//
#include <hip/hip_runtime.h>

#define EPSV 1e-5f

// DPP-based full-wave sum (verified correct in round 2).
#define DPP_XADD(v, ctrl)                                                  \
    v += __int_as_float(__builtin_amdgcn_update_dpp(                       \
        0, __float_as_int(v), ctrl, 0xF, 0xF, false))

__device__ __forceinline__ float wave_allsum(float v) {
    DPP_XADD(v, 0x128);   // row_ror:8
    DPP_XADD(v, 0x124);   // row_ror:4
    DPP_XADD(v, 0x122);   // row_ror:2
    DPP_XADD(v, 0x121);   // row_ror:1
    DPP_XADD(v, 0x142);   // row_bcast15
    DPP_XADD(v, 0x143);   // row_bcast31
    return __int_as_float(__builtin_amdgcn_readlane(__float_as_int(v), 63));
}

// ============================================================
// Phase 1: input-to-hidden TCL3D (+LN in/out) for all (t,n).
// One block per tb, 256 threads. Conflict-free transposed LDS,
// scalar b32 writes/reads, all accesses exactly 2-way (free).
// Normalization folded into stage 1 (no Xs rewrite pass).
// ============================================================
__global__ __launch_bounds__(256) void wx_kernel(
    const float* __restrict__ x,
    const float* __restrict__ Wfa, const float* __restrict__ Wfb,
    const float* __restrict__ Wfc,
    const float* __restrict__ Wba, const float* __restrict__ Wbb,
    const float* __restrict__ Wbc,
    const float* __restrict__ lniw, const float* __restrict__ lnib,
    const float* __restrict__ lnow, const float* __restrict__ lnob,
    float* __restrict__ wxo)
{
    __shared__ float Xs[4096];
    __shared__ float S1[2048];
    __shared__ float S2[1024];
    __shared__ float faS[384], fbS[384], fcS[384];
    __shared__ float baS[24], bbS[24], bcS[24];
    __shared__ float red[16];

    const int tid  = threadIdx.x;
    const int wid  = tid >> 6, lane = tid & 63;
    const size_t tb = blockIdx.x;
    const float* xp = x + tb * 4096;

    float s = 0.f, s2 = 0.f;
    for (int i = tid; i < 4096; i += 256) {
        float v = xp[i];
        Xs[i] = v;
        s += v; s2 += v * v;
    }
    for (int i = tid; i < 384; i += 256) {
        faS[i] = Wfa[i]; fbS[i] = Wfb[i]; fcS[i] = Wfc[i];
    }
    if (tid < 24) { baS[tid] = Wba[tid]; bbS[tid] = Wbb[tid]; bcS[tid] = Wbc[tid]; }

    __syncthreads();
    #pragma unroll
    for (int off = 32; off > 0; off >>= 1) {
        s  += __shfl_down(s,  off);
        s2 += __shfl_down(s2, off);
    }
    if (lane == 0) { red[wid] = s; red[8 + wid] = s2; }
    __syncthreads();
    s  = red[0] + red[1] + red[2] + red[3];
    s2 = red[8] + red[9] + red[10] + red[11];
    const float muX = s * (1.f / 4096.f);
    const float rsX = rsqrtf(fmaxf(s2 * (1.f / 4096.f) - muX * muX, 0.f) + EPSV);

    for (int g = 0; g < 3; ++g) {
        // ---- stage 1: contract a(16) -> t1[(b,c),p]
        {
            float acc[8] = {0,0,0,0,0,0,0,0};
            const int rest = tid;                      // b*16+c
            const float* lw = lniw + g * 4096;
            const float* lb = lnib + g * 4096;
            #pragma unroll
            for (int m = 0; m < 16; ++m) {
                const float xn = (Xs[m*256 + rest] - muX) * rsX;
                const float xv = fmaf(xn, lw[m*256 + rest], lb[m*256 + rest]);
                #pragma unroll
                for (int p = 0; p < 8; ++p)
                    acc[p] = fmaf(xv, faS[(g*16 + m)*8 + p], acc[p]);
            }
            #pragma unroll
            for (int p = 0; p < 8; ++p)
                S1[p*256 + (rest ^ (p << 3))] = acc[p];
        }
        __syncthreads();
        // ---- stage 2: contract b(16) -> t2[(c,p),q]
        {
            float acc[4] = {0,0,0,0};
            const int rest2 = tid & 127, qh = tid >> 7;  // rest2 = c*8+p
            const int c2 = rest2 >> 3, p2 = rest2 & 7;
            #pragma unroll
            for (int m = 0; m < 16; ++m) {
                const float xv = S1[p2*256 + (((m << 4) | c2) ^ (p2 << 3))];
                #pragma unroll
                for (int j = 0; j < 4; ++j)
                    acc[j] = fmaf(xv, fbS[(g*16 + m)*8 + qh*4 + j], acc[j]);
            }
            #pragma unroll
            for (int j = 0; j < 4; ++j) {
                const int q = qh*4 + j;
                S2[q*128 + (rest2 ^ (q << 3))] = acc[j];
            }
        }
        __syncthreads();
        // ---- stage 3: contract c(16) -> y[(p,q),r] + rank-1 bias (regs)
        float v0, v1; int idx0;
        {
            float acc[2] = {0, 0};
            const int rest3 = tid & 63, rh = tid >> 6;   // rest3 = p*8+q
            const int q3 = rest3 & 7, pp = rest3 >> 3;
            #pragma unroll
            for (int m = 0; m < 16; ++m) {
                const float xv = S2[q3*128 + (((m << 3) | pp) ^ (q3 << 3))];
                #pragma unroll
                for (int j = 0; j < 2; ++j)
                    acc[j] = fmaf(xv, fcS[(g*16 + m)*8 + rh*2 + j], acc[j]);
            }
            const float bpq = baS[g*8 + pp] * bbS[g*8 + q3];
            v0 = acc[0] + bpq * bcS[g*8 + rh*2 + 0];
            v1 = acc[1] + bpq * bcS[g*8 + rh*2 + 1];
            idx0 = rest3 * 8 + rh * 2;
        }
        // ---- std over 512, lnout affine, store
        float t = v0 + v1, t2 = v0*v0 + v1*v1;
        __syncthreads();
        #pragma unroll
        for (int off = 32; off > 0; off >>= 1) {
            t  += __shfl_down(t,  off);
            t2 += __shfl_down(t2, off);
        }
        if (lane == 0) { red[wid] = t; red[8 + wid] = t2; }
        __syncthreads();
        t  = red[0] + red[1] + red[2] + red[3];
        t2 = red[8] + red[9] + red[10] + red[11];
        const float mu  = t * (1.f / 512.f);
        const float var = fmaxf(t2 * (1.f / 512.f) - mu * mu, 0.f);
        const float rs  = rsqrtf(var + EPSV);
        float* wp = wxo + (tb * 3 + g) * 512;
        const float2 lw2 = *(const float2*)(lnow + g*512 + idx0);
        const float2 lb2 = *(const float2*)(lnob + g*512 + idx0);
        float2 o2;
        o2.x = fmaf((v0 - mu) * rs, lw2.x, lb2.x);
        o2.y = fmaf((v1 - mu) * rs, lw2.y, lb2.y);
        *(float2*)(wp + idx0) = o2;
        // next gate's S1 writes are ordered behind the reduce's barriers
    }
}

// ============================================================
// Phase 2: sequential GRU scan. One block per sample, 3 waves
// = 3 gates. h redundant in regs per wave; U-factors in LDS
// read as broadcast b128 (opaque offset defeats LICM so they
// are NOT hoisted into registers); data buffers use the
// transposed+swizzled scalar scheme (all LDS 2-way = free).
// One __syncthreads per step.
// Weight layout: Wt4[gate][stage][m*2 + (q>=4)] -> gate stride
// 48 float4, stage stride 16 float4 (round-3 bug: used 12/4).
// ============================================================
__global__ __launch_bounds__(192, 1) void scan_kernel(
    const float* __restrict__ wx,     // [T*B, 3, 512]
    const float* __restrict__ h0,     // [B, 512]
    const float* __restrict__ Ufa, const float* __restrict__ Ufb,
    const float* __restrict__ Ufc,
    const float* __restrict__ Uba, const float* __restrict__ Ubb,
    const float* __restrict__ Ubc,
    const float* __restrict__ lniw, const float* __restrict__ lnib,
    const float* __restrict__ lnow, const float* __restrict__ lnob,
    float* __restrict__ out,          // [T*B, 512]
    int T, int B)
{
    const int n    = blockIdx.x;
    const int tid  = threadIdx.x;
    const int g    = tid >> 6;        // wave = gate
    const int lane = tid & 63;

    __shared__ float4 Wt4[3][3][16];  // [gate][stage][m*2 + (q>=4)]
    __shared__ float hgS[3][512];
    __shared__ float T1S[3][512];
    __shared__ float T2S[3][512];
    __shared__ float UhS[2][3][512];

    if (tid < 48) {
        Wt4[tid >> 4][0][tid & 15] = ((const float4*)Ufa)[tid];
    } else if (tid < 96) {
        const int i = tid - 48;
        Wt4[i >> 4][1][i & 15] = ((const float4*)Ufb)[i];
    } else if (tid < 144) {
        const int i = tid - 96;
        Wt4[i >> 4][2][i & 15] = ((const float4*)Ufc)[i];
    }

    // ---- per-element coefficients (small, stays in regs) ----
    float lnw[8], lnb[8], low8[8], lob8[8], ub[8];
    {
        const int p_ = lane >> 3, q_ = lane & 7;
        const float bpq = Uba[g*8 + p_] * Ubb[g*8 + q_];
        #pragma unroll
        for (int k = 0; k < 8; ++k) {
            lnw[k]  = lniw[g*512 + lane*8 + k];
            lnb[k]  = lnib[g*512 + lane*8 + k];
            low8[k] = lnow[g*512 + lane*8 + k];
            lob8[k] = lnob[g*512 + lane*8 + k];
            ub[k]   = bpq * Ubc[g*8 + k];
        }
    }

    // ---- conflict-free transposed LDS addressing ----
    // logical i -> phys (i&7)*64 + ((i>>3) ^ ((i&7)<<2))
    int wb[8], rb2[8];
    #pragma unroll
    for (int j = 0; j < 8; ++j) wb[j] = j*64 + (lane ^ (j << 2));
    {
        const int c = lane & 7, r = lane >> 3;
        #pragma unroll
        for (int m = 0; m < 8; ++m)
            rb2[m] = c*64 + (((m << 3) | r) ^ (c << 2));
    }

    // ---- h in regs (element lane*8+k), redundant per wave ----
    float hv[8];
    {
        const float4 a = *(const float4*)(h0 + n*512 + lane*8);
        const float4 b = *(const float4*)(h0 + n*512 + lane*8 + 4);
        hv[0]=a.x; hv[1]=a.y; hv[2]=a.z; hv[3]=a.w;
        hv[4]=b.x; hv[5]=b.y; hv[6]=b.z; hv[7]=b.w;
    }

    float pf[3][8];
#define LOADWX(TT)                                                         \
    {                                                                      \
        const float* base_ = wx + (((size_t)(TT) * B + n) * 3) * 512       \
                             + lane * 8;                                   \
        _Pragma("unroll")                                                  \
        for (int gg = 0; gg < 3; ++gg) {                                   \
            const float4 A_ = *(const float4*)(base_ + gg*512);            \
            const float4 B_ = *(const float4*)(base_ + gg*512 + 4);        \
            pf[gg][0]=A_.x; pf[gg][1]=A_.y; pf[gg][2]=A_.z; pf[gg][3]=A_.w;\
            pf[gg][4]=B_.x; pf[gg][5]=B_.y; pf[gg][6]=B_.z; pf[gg][7]=B_.w;\
        }                                                                  \
    }

    // Weight base pointer with opaque zero offset, refreshed every
    // iteration inside PIPELINE: prevents LICM from hoisting the 144
    // broadcast weight loads out of the t-loop (which would re-create
    // the register-pressure spill seen in rounds 1-2).
    int wz = 0;

#define STAGE(INBUF, WOFF, AOUT)                                           \
    _Pragma("unroll")                                                      \
    for (int m = 0; m < 8; ++m) {                                          \
        const float xv = INBUF[g][rb2[m]];                                 \
        const float4 wlo = wp4_[(WOFF) + 2*m];                             \
        const float4 whi = wp4_[(WOFF) + 2*m + 1];                         \
        AOUT[0] = fmaf(xv, wlo.x, AOUT[0]);                                \
        AOUT[1] = fmaf(xv, wlo.y, AOUT[1]);                                \
        AOUT[2] = fmaf(xv, wlo.z, AOUT[2]);                                \
        AOUT[3] = fmaf(xv, wlo.w, AOUT[3]);                                \
        AOUT[4] = fmaf(xv, whi.x, AOUT[4]);                                \
        AOUT[5] = fmaf(xv, whi.y, AOUT[5]);                                \
        AOUT[6] = fmaf(xv, whi.z, AOUT[6]);                                \
        AOUT[7] = fmaf(xv, whi.w, AOUT[7]);                                \
    }

#define PIPELINE(PAR)                                                      \
    {                                                                      \
        asm volatile("" : "+v"(wz));                                       \
        const float4* wp4_ = (const float4*)Wt4 + (size_t)g*48 + wz;       \
        float sA = 0.f, sB = 0.f;                                          \
        _Pragma("unroll")                                                  \
        for (int k = 0; k < 8; ++k) { sA += hv[k]; sB += hv[k]*hv[k]; }    \
        sA = wave_allsum(sA); sB = wave_allsum(sB);                        \
        const float mu_ = sA * (1.f/512.f);                                \
        const float rs_ = rsqrtf(fmaxf(sB*(1.f/512.f) - mu_*mu_, 0.f)      \
                                 + EPSV);                                  \
        _Pragma("unroll")                                                  \
        for (int k = 0; k < 8; ++k)                                        \
            hgS[g][wb[k]] = fmaf((hv[k]-mu_)*rs_, lnw[k], lnb[k]);         \
        float a_[8];                                                       \
        _Pragma("unroll") for (int k = 0; k < 8; ++k) a_[k] = 0.f;         \
        STAGE(hgS, 0, a_)                                                  \
        _Pragma("unroll")                                                  \
        for (int k = 0; k < 8; ++k) { T1S[g][wb[k]] = a_[k]; a_[k] = 0.f; }\
        STAGE(T1S, 16, a_)                                                 \
        _Pragma("unroll")                                                  \
        for (int k = 0; k < 8; ++k) { T2S[g][wb[k]] = a_[k]; a_[k] = 0.f; }\
        STAGE(T2S, 32, a_)                                                 \
        float sC = 0.f, sD = 0.f;                                          \
        _Pragma("unroll")                                                  \
        for (int k = 0; k < 8; ++k) {                                      \
            a_[k] += ub[k]; sC += a_[k]; sD += a_[k]*a_[k];                \
        }                                                                  \
        sC = wave_allsum(sC); sD = wave_allsum(sD);                        \
        const float mu2_ = sC * (1.f/512.f);                               \
        const float rs2_ = rsqrtf(fmaxf(sD*(1.f/512.f) - mu2_*mu2_, 0.f)   \
                                  + EPSV);                                 \
        _Pragma("unroll")                                                  \
        for (int k = 0; k < 8; ++k)                                        \
            UhS[PAR][g][wb[k]] = fmaf((a_[k]-mu2_)*rs2_, low8[k], lob8[k]);\
    }

#define COMBINE(PAR)                                                       \
    {                                                                      \
        float u0[8], u1[8], u2[8];                                         \
        _Pragma("unroll")                                                  \
        for (int k = 0; k < 8; ++k) {                                      \
            u0[k] = UhS[PAR][0][wb[k]];                                    \
            u1[k] = UhS[PAR][1][wb[k]];                                    \
            u2[k] = UhS[PAR][2][wb[k]];                                    \
        }                                                                  \
        _Pragma("unroll")                                                  \
        for (int k = 0; k < 8; ++k) {                                      \
            const float r_  = 1.f/(1.f + __expf(-(pf[0][k] + u0[k])));     \
            const float z_  = 1.f/(1.f + __expf(-(pf[1][k] + u1[k])));     \
            const float e2_ = __expf(2.f*(pf[2][k] + r_*u2[k]));           \
            const float nn_ = 1.f - 2.f/(e2_ + 1.f);                       \
            hv[k] = (1.f - z_)*nn_ + z_*hv[k];                             \
        }                                                                  \
    }

    LOADWX(0);
    __syncthreads();           // Wt4 visible to all waves
    PIPELINE(0);               // Uh(h0) -> parity 0

    for (int t = 0; t < T; ++t) {
        __syncthreads();       // UhS[t&1] (all 3 planes) ready
        COMBINE(t & 1);
        if (g == 0) {
            float* op = out + ((size_t)t * B + n) * 512 + lane*8;
            *(float4*)op     = make_float4(hv[0], hv[1], hv[2], hv[3]);
            *(float4*)(op+4) = make_float4(hv[4], hv[5], hv[6], hv[7]);
        }
        if (t + 1 < T) {
            LOADWX(t + 1);              // issue-early; consumed next step
            PIPELINE((t + 1) & 1);      // Uh(h_{t+1}) into other parity
        }
    }
#undef LOADWX
#undef STAGE
#undef PIPELINE
#undef COMBINE
}

extern "C" void kernel_launch(void* const* d_in, const int* in_sizes, int n_in,
                              void* d_out, int out_size, void* d_ws, size_t ws_size,
                              hipStream_t stream)
{
    const float* x    = (const float*)d_in[0];
    const float* h0   = (const float*)d_in[1];
    const float* Wfa  = (const float*)d_in[2];
    const float* Wfb  = (const float*)d_in[3];
    const float* Wfc  = (const float*)d_in[4];
    const float* Wba  = (const float*)d_in[5];
    const float* Wbb  = (const float*)d_in[6];
    const float* Wbc  = (const float*)d_in[7];
    const float* Wliw = (const float*)d_in[8];
    const float* Wlib = (const float*)d_in[9];
    const float* Wlow = (const float*)d_in[10];
    const float* Wlob = (const float*)d_in[11];
    const float* Ufa  = (const float*)d_in[12];
    const float* Ufb  = (const float*)d_in[13];
    const float* Ufc  = (const float*)d_in[14];
    const float* Uba  = (const float*)d_in[15];
    const float* Ubb  = (const float*)d_in[16];
    const float* Ubc  = (const float*)d_in[17];
    const float* Uliw = (const float*)d_in[18];
    const float* Ulib = (const float*)d_in[19];
    const float* Ulow = (const float*)d_in[20];
    const float* Ulob = (const float*)d_in[21];

    const int B = in_sizes[1] / 512;            // 16
    const int T = in_sizes[0] / (B * 4096);     // 512

    float* wxws = (float*)d_ws;                 // [T*B, 3, 512] scratch
    float* out  = (float*)d_out;

    wx_kernel<<<T * B, 256, 0, stream>>>(x, Wfa, Wfb, Wfc, Wba, Wbb, Wbc,
                                         Wliw, Wlib, Wlow, Wlob, wxws);
    scan_kernel<<<B, 192, 0, stream>>>(wxws, h0, Ufa, Ufb, Ufc, Uba, Ubb, Ubc,
                                       Uliw, Ulib, Ulow, Ulob, out, T, B);
}

// Round 5
// 933.174 us; speedup vs baseline: 1.4933x; 1.4933x over previous
//
#include <hip/hip_runtime.h>

#define EPSV 1e-5f

// DPP-based full-wave sum (verified correct rounds 2/4).
#define DPP_XADD(v, ctrl)                                                  \
    v += __int_as_float(__builtin_amdgcn_update_dpp(                       \
        0, __float_as_int(v), ctrl, 0xF, 0xF, false))

__device__ __forceinline__ float wave_allsum(float v) {
    DPP_XADD(v, 0x128);   // row_ror:8
    DPP_XADD(v, 0x124);   // row_ror:4
    DPP_XADD(v, 0x122);   // row_ror:2
    DPP_XADD(v, 0x121);   // row_ror:1
    DPP_XADD(v, 0x142);   // row_bcast15
    DPP_XADD(v, 0x143);   // row_bcast31
    return __int_as_float(__builtin_amdgcn_readlane(__float_as_int(v), 63));
}

// ============================================================
// Phase 1: input-to-hidden TCL3D (+LN in/out) for all (t,n).
// One block per tb, 256 threads. Factor weights read via
// UNIFORM global addresses -> s_load (scalar pipe), no LDS
// staging. Data transposes: conflict-free b32 scheme (R4).
// ============================================================
__global__ __launch_bounds__(256) void wx_kernel(
    const float* __restrict__ x,
    const float* __restrict__ Wfa, const float* __restrict__ Wfb,
    const float* __restrict__ Wfc,
    const float* __restrict__ Wba, const float* __restrict__ Wbb,
    const float* __restrict__ Wbc,
    const float* __restrict__ lniw, const float* __restrict__ lnib,
    const float* __restrict__ lnow, const float* __restrict__ lnob,
    float* __restrict__ wxo)
{
    __shared__ float Xs[4096];
    __shared__ float S1[2048];
    __shared__ float S2[1024];
    __shared__ float baS[24], bbS[24], bcS[24];
    __shared__ float red[16];

    const int tid  = threadIdx.x;
    const int wid  = tid >> 6, lane = tid & 63;
    const size_t tb = blockIdx.x;
    const float* xp = x + tb * 4096;

    float s = 0.f, s2 = 0.f;
    for (int i = tid; i < 4096; i += 256) {
        float v = xp[i];
        Xs[i] = v;
        s += v; s2 += v * v;
    }
    if (tid < 24) { baS[tid] = Wba[tid]; bbS[tid] = Wbb[tid]; bcS[tid] = Wbc[tid]; }

    __syncthreads();
    #pragma unroll
    for (int off = 32; off > 0; off >>= 1) {
        s  += __shfl_down(s,  off);
        s2 += __shfl_down(s2, off);
    }
    if (lane == 0) { red[wid] = s; red[8 + wid] = s2; }
    __syncthreads();
    s  = red[0] + red[1] + red[2] + red[3];
    s2 = red[8] + red[9] + red[10] + red[11];
    const float muX = s * (1.f / 4096.f);
    const float rsX = rsqrtf(fmaxf(s2 * (1.f / 4096.f) - muX * muX, 0.f) + EPSV);

    // per-wave-uniform sub-indices (readfirstlane -> provably uniform,
    // so weight loads below become SMEM s_loads)
    const int qh = __builtin_amdgcn_readfirstlane(tid >> 7);   // 0..1
    const int rh = __builtin_amdgcn_readfirstlane(tid >> 6);   // 0..3

    for (int g = 0; g < 3; ++g) {
        // ---- stage 1: contract a(16) -> t1[(b,c),p]
        {
            float acc[8] = {0,0,0,0,0,0,0,0};
            const int rest = tid;                      // b*16+c
            const float* lw = lniw + g * 4096;
            const float* lb = lnib + g * 4096;
            #pragma unroll
            for (int m = 0; m < 16; ++m) {
                const float xn = (Xs[m*256 + rest] - muX) * rsX;
                const float xv = fmaf(xn, lw[m*256 + rest], lb[m*256 + rest]);
                #pragma unroll
                for (int p = 0; p < 8; ++p)
                    acc[p] = fmaf(xv, Wfa[(g*16 + m)*8 + p], acc[p]);
            }
            #pragma unroll
            for (int p = 0; p < 8; ++p)
                S1[p*256 + (rest ^ (p << 3))] = acc[p];
        }
        __syncthreads();
        // ---- stage 2: contract b(16) -> t2[(c,p),q]
        {
            float acc[4] = {0,0,0,0};
            const int rest2 = tid & 127;               // c*8+p
            const int c2 = rest2 >> 3, p2 = rest2 & 7;
            #pragma unroll
            for (int m = 0; m < 16; ++m) {
                const float xv = S1[p2*256 + (((m << 4) | c2) ^ (p2 << 3))];
                #pragma unroll
                for (int j = 0; j < 4; ++j)
                    acc[j] = fmaf(xv, Wfb[(g*16 + m)*8 + qh*4 + j], acc[j]);
            }
            #pragma unroll
            for (int j = 0; j < 4; ++j) {
                const int q = qh*4 + j;
                S2[q*128 + (rest2 ^ (q << 3))] = acc[j];
            }
        }
        __syncthreads();
        // ---- stage 3: contract c(16) -> y[(p,q),r] + rank-1 bias (regs)
        float v0, v1; int idx0;
        {
            float acc[2] = {0, 0};
            const int rest3 = tid & 63;                // p*8+q
            const int q3 = rest3 & 7, pp = rest3 >> 3;
            #pragma unroll
            for (int m = 0; m < 16; ++m) {
                const float xv = S2[q3*128 + (((m << 3) | pp) ^ (q3 << 3))];
                #pragma unroll
                for (int j = 0; j < 2; ++j)
                    acc[j] = fmaf(xv, Wfc[(g*16 + m)*8 + rh*2 + j], acc[j]);
            }
            const float bpq = baS[g*8 + pp] * bbS[g*8 + q3];
            v0 = acc[0] + bpq * bcS[g*8 + rh*2 + 0];
            v1 = acc[1] + bpq * bcS[g*8 + rh*2 + 1];
            idx0 = rest3 * 8 + rh * 2;
        }
        // ---- std over 512, lnout affine, store
        float t = v0 + v1, t2 = v0*v0 + v1*v1;
        __syncthreads();
        #pragma unroll
        for (int off = 32; off > 0; off >>= 1) {
            t  += __shfl_down(t,  off);
            t2 += __shfl_down(t2, off);
        }
        if (lane == 0) { red[wid] = t; red[8 + wid] = t2; }
        __syncthreads();
        t  = red[0] + red[1] + red[2] + red[3];
        t2 = red[8] + red[9] + red[10] + red[11];
        const float mu  = t * (1.f / 512.f);
        const float var = fmaxf(t2 * (1.f / 512.f) - mu * mu, 0.f);
        const float rs  = rsqrtf(var + EPSV);
        float* wp = wxo + (tb * 3 + g) * 512;
        const float2 lw2 = *(const float2*)(lnow + g*512 + idx0);
        const float2 lb2 = *(const float2*)(lnob + g*512 + idx0);
        float2 o2;
        o2.x = fmaf((v0 - mu) * rs, lw2.x, lb2.x);
        o2.y = fmaf((v1 - mu) * rs, lw2.y, lb2.y);
        *(float2*)(wp + idx0) = o2;
    }
}

// ============================================================
// Phase 2: sequential GRU scan. One block per sample, 3 waves
// = 3 gates. h redundant in regs per wave. U-factors read via
// UNIFORM (readfirstlane) global addresses -> s_load into
// SGPRs, consumed as the scalar operand of v_fma (zero DS/VGPR
// cost). Data transposes: conflict-free b32 scheme (R4).
// One __syncthreads per step, UhS parity double-buffered.
// ============================================================
__global__ __launch_bounds__(192, 1) void scan_kernel(
    const float* __restrict__ wx,     // [T*B, 3, 512]
    const float* __restrict__ h0,     // [B, 512]
    const float* __restrict__ Ufa, const float* __restrict__ Ufb,
    const float* __restrict__ Ufc,
    const float* __restrict__ Uba, const float* __restrict__ Ubb,
    const float* __restrict__ Ubc,
    const float* __restrict__ lniw, const float* __restrict__ lnib,
    const float* __restrict__ lnow, const float* __restrict__ lnob,
    float* __restrict__ out,          // [T*B, 512]
    int T, int B)
{
    const int n    = blockIdx.x;
    const int tid  = threadIdx.x;
    const int lane = tid & 63;
    // wave-uniform gate id: makes all weight addresses uniform -> SMEM
    const int gu   = __builtin_amdgcn_readfirstlane(tid >> 6);

    __shared__ float hgS[3][512];
    __shared__ float T1S[3][512];
    __shared__ float T2S[3][512];
    __shared__ float UhS[2][3][512];

    const float* __restrict__ WA = Ufa + gu * 64;   // uniform bases
    const float* __restrict__ WB = Ufb + gu * 64;
    const float* __restrict__ WC = Ufc + gu * 64;

    // ---- per-element coefficients (lane-varying, stay in VGPRs) ----
    float lnw[8], lnb[8], low8[8], lob8[8], ub[8];
    {
        const int p_ = lane >> 3, q_ = lane & 7;
        const float bpq = Uba[gu*8 + p_] * Ubb[gu*8 + q_];
        #pragma unroll
        for (int k = 0; k < 8; ++k) {
            lnw[k]  = lniw[gu*512 + lane*8 + k];
            lnb[k]  = lnib[gu*512 + lane*8 + k];
            low8[k] = lnow[gu*512 + lane*8 + k];
            lob8[k] = lnob[gu*512 + lane*8 + k];
            ub[k]   = bpq * Ubc[gu*8 + k];
        }
    }

    // ---- conflict-free transposed LDS addressing (verified R4) ----
    // logical i -> phys (i&7)*64 + ((i>>3) ^ ((i&7)<<2))
    int wb[8], rb2[8];
    #pragma unroll
    for (int j = 0; j < 8; ++j) wb[j] = j*64 + (lane ^ (j << 2));
    {
        const int c = lane & 7, r = lane >> 3;
        #pragma unroll
        for (int m = 0; m < 8; ++m)
            rb2[m] = c*64 + (((m << 3) | r) ^ (c << 2));
    }

    // ---- h in regs (element lane*8+k), redundant per wave ----
    float hv[8];
    {
        const float4 a = *(const float4*)(h0 + n*512 + lane*8);
        const float4 b = *(const float4*)(h0 + n*512 + lane*8 + 4);
        hv[0]=a.x; hv[1]=a.y; hv[2]=a.z; hv[3]=a.w;
        hv[4]=b.x; hv[5]=b.y; hv[6]=b.z; hv[7]=b.w;
    }

    float pf[3][8];
#define LOADWX(TT)                                                         \
    {                                                                      \
        const float* base_ = wx + (((size_t)(TT) * B + n) * 3) * 512       \
                             + lane * 8;                                   \
        _Pragma("unroll")                                                  \
        for (int gg = 0; gg < 3; ++gg) {                                   \
            const float4 A_ = *(const float4*)(base_ + gg*512);            \
            const float4 B_ = *(const float4*)(base_ + gg*512 + 4);       \
            pf[gg][0]=A_.x; pf[gg][1]=A_.y; pf[gg][2]=A_.z; pf[gg][3]=A_.w;\
            pf[gg][4]=B_.x; pf[gg][5]=B_.y; pf[gg][6]=B_.z; pf[gg][7]=B_.w;\
        }                                                                  \
    }

#define STAGE(INBUF, WPTR, AOUT)                                           \
    _Pragma("unroll")                                                      \
    for (int m = 0; m < 8; ++m) {                                          \
        const float xv = INBUF[gu][rb2[m]];                                \
        _Pragma("unroll")                                                  \
        for (int q = 0; q < 8; ++q)                                        \
            AOUT[q] = fmaf(xv, WPTR[m*8 + q], AOUT[q]);                    \
    }

#define PIPELINE(PAR)                                                      \
    {                                                                      \
        float sA = 0.f, sB = 0.f;                                          \
        _Pragma("unroll")                                                  \
        for (int k = 0; k < 8; ++k) { sA += hv[k]; sB += hv[k]*hv[k]; }    \
        sA = wave_allsum(sA); sB = wave_allsum(sB);                        \
        const float mu_ = sA * (1.f/512.f);                                \
        const float rs_ = rsqrtf(fmaxf(sB*(1.f/512.f) - mu_*mu_, 0.f)      \
                                 + EPSV);                                  \
        _Pragma("unroll")                                                  \
        for (int k = 0; k < 8; ++k)                                        \
            hgS[gu][wb[k]] = fmaf((hv[k]-mu_)*rs_, lnw[k], lnb[k]);        \
        float a_[8];                                                       \
        _Pragma("unroll") for (int k = 0; k < 8; ++k) a_[k] = 0.f;         \
        STAGE(hgS, WA, a_)                                                 \
        _Pragma("unroll")                                                  \
        for (int k = 0; k < 8; ++k) { T1S[gu][wb[k]] = a_[k]; a_[k] = 0.f;}\
        STAGE(T1S, WB, a_)                                                 \
        _Pragma("unroll")                                                  \
        for (int k = 0; k < 8; ++k) { T2S[gu][wb[k]] = a_[k]; a_[k] = 0.f;}\
        STAGE(T2S, WC, a_)                                                 \
        float sC = 0.f, sD = 0.f;                                          \
        _Pragma("unroll")                                                  \
        for (int k = 0; k < 8; ++k) {                                      \
            a_[k] += ub[k]; sC += a_[k]; sD += a_[k]*a_[k];                \
        }                                                                  \
        sC = wave_allsum(sC); sD = wave_allsum(sD);                        \
        const float mu2_ = sC * (1.f/512.f);                               \
        const float rs2_ = rsqrtf(fmaxf(sD*(1.f/512.f) - mu2_*mu2_, 0.f)   \
                                  + EPSV);                                 \
        _Pragma("unroll")                                                  \
        for (int k = 0; k < 8; ++k)                                        \
            UhS[PAR][gu][wb[k]] = fmaf((a_[k]-mu2_)*rs2_, low8[k],         \
                                       lob8[k]);                           \
    }

#define COMBINE(PAR)                                                       \
    {                                                                      \
        float u0[8], u1[8], u2[8];                                         \
        _Pragma("unroll")                                                  \
        for (int k = 0; k < 8; ++k) {                                      \
            u0[k] = UhS[PAR][0][wb[k]];                                    \
            u1[k] = UhS[PAR][1][wb[k]];                                    \
            u2[k] = UhS[PAR][2][wb[k]];                                    \
        }                                                                  \
        _Pragma("unroll")                                                  \
        for (int k = 0; k < 8; ++k) {                                      \
            const float er_ = __expf(-(pf[0][k] + u0[k]));                 \
            const float r_  = __builtin_amdgcn_rcpf(1.f + er_);            \
            const float ez_ = __expf(-(pf[1][k] + u1[k]));                 \
            const float z_  = __builtin_amdgcn_rcpf(1.f + ez_);            \
            const float e2_ = __expf(2.f*(pf[2][k] + r_*u2[k]));           \
            const float nn_ = 1.f - 2.f*__builtin_amdgcn_rcpf(e2_ + 1.f);  \
            hv[k] = (1.f - z_)*nn_ + z_*hv[k];                             \
        }                                                                  \
    }

    LOADWX(0);
    PIPELINE(0);               // Uh(h0) -> parity 0

    for (int t = 0; t < T; ++t) {
        __syncthreads();       // UhS[t&1] (all 3 planes) ready
        COMBINE(t & 1);
        if (gu == 0) {
            float* op = out + ((size_t)t * B + n) * 512 + lane*8;
            *(float4*)op     = make_float4(hv[0], hv[1], hv[2], hv[3]);
            *(float4*)(op+4) = make_float4(hv[4], hv[5], hv[6], hv[7]);
        }
        if (t + 1 < T) {
            LOADWX(t + 1);              // issue-early; consumed next step
            PIPELINE((t + 1) & 1);      // Uh(h_{t+1}) into other parity
        }
    }
#undef LOADWX
#undef STAGE
#undef PIPELINE
#undef COMBINE
}

extern "C" void kernel_launch(void* const* d_in, const int* in_sizes, int n_in,
                              void* d_out, int out_size, void* d_ws, size_t ws_size,
                              hipStream_t stream)
{
    const float* x    = (const float*)d_in[0];
    const float* h0   = (const float*)d_in[1];
    const float* Wfa  = (const float*)d_in[2];
    const float* Wfb  = (const float*)d_in[3];
    const float* Wfc  = (const float*)d_in[4];
    const float* Wba  = (const float*)d_in[5];
    const float* Wbb  = (const float*)d_in[6];
    const float* Wbc  = (const float*)d_in[7];
    const float* Wliw = (const float*)d_in[8];
    const float* Wlib = (const float*)d_in[9];
    const float* Wlow = (const float*)d_in[10];
    const float* Wlob = (const float*)d_in[11];
    const float* Ufa  = (const float*)d_in[12];
    const float* Ufb  = (const float*)d_in[13];
    const float* Ufc  = (const float*)d_in[14];
    const float* Uba  = (const float*)d_in[15];
    const float* Ubb  = (const float*)d_in[16];
    const float* Ubc  = (const float*)d_in[17];
    const float* Uliw = (const float*)d_in[18];
    const float* Ulib = (const float*)d_in[19];
    const float* Ulow = (const float*)d_in[20];
    const float* Ulob = (const float*)d_in[21];

    const int B = in_sizes[1] / 512;            // 16
    const int T = in_sizes[0] / (B * 4096);     // 512

    float* wxws = (float*)d_ws;                 // [T*B, 3, 512] scratch
    float* out  = (float*)d_out;

    wx_kernel<<<T * B, 256, 0, stream>>>(x, Wfa, Wfb, Wfc, Wba, Wbb, Wbc,
                                         Wliw, Wlib, Wlow, Wlob, wxws);
    scan_kernel<<<B, 192, 0, stream>>>(wxws, h0, Ufa, Ufb, Ufc, Uba, Ubb, Ubc,
                                       Uliw, Ulib, Ulow, Ulob, out, T, B);
}